// Round 1
// baseline (755.264 us; speedup 1.0000x reference)
//
#include <hip/hip_runtime.h>

#define NN 1024
#define TT 256
#define MAXDEG 96

typedef unsigned short u16;
typedef unsigned int u32;

// ---------- prep pass 1: per-chunk nonzero counts of each adj column ----------
__global__ __launch_bounds__(64) void count_kernel(const float* __restrict__ adj,
                                                   int* __restrict__ cnt_part)
{
    int tid = blockIdx.x * 64 + threadIdx.x;   // 0..16383
    int chunk = tid >> 10;                     // 16 chunks of 64 rows
    int n = tid & 1023;                        // column
    int c = 0;
    for (int j = 0; j < 64; ++j)
        c += (adj[(chunk * 64 + j) * NN + n] != 0.0f) ? 1 : 0;
    cnt_part[chunk * NN + n] = c;
}

// ---------- prep pass 2: deterministic fill of interleaved neighbor table ----------
// layout: group g (8 neighbors), node n, slot k  ->  nbr8[(g<<13) + (n<<3) + k]
// so one thread's group g is a single aligned 16B load (8 ushorts).
__global__ __launch_bounds__(64) void fill_kernel(const float* __restrict__ adj,
                                                  const int* __restrict__ cnt_part,
                                                  u16* __restrict__ nbr8,
                                                  float* __restrict__ indeg,
                                                  int* __restrict__ pdeg)
{
    int tid = blockIdx.x * 64 + threadIdx.x;
    int chunk = tid >> 10;
    int n = tid & 1023;
    int start = 0, total = 0;
    for (int c = 0; c < 16; ++c) {
        int v = cnt_part[c * NN + n];
        if (c < chunk) start += v;
        total += v;
    }
    int pos = start;
    for (int j = 0; j < 64; ++j) {
        int m = chunk * 64 + j;
        if (adj[m * NN + n] != 0.0f) {
            if (pos < MAXDEG) nbr8[((pos >> 3) << 13) + (n << 3) + (pos & 7)] = (u16)m;
            ++pos;
        }
    }
    if (chunk == 0) {
        indeg[n] = (float)total;
        int ct = total < MAXDEG ? total : MAXDEG;
        int pd = (ct + 7) & ~7;
        for (int j = ct; j < pd; ++j)
            nbr8[((j >> 3) << 13) + (n << 3) + (j & 7)] = (u16)NN;  // sentinel -> x=0
        pdeg[n] = pd;
    }
}

// ---------- main simulation: one block per sequence, one thread per node ----------
__global__ __launch_bounds__(1024) void sim_kernel(
    const float* __restrict__ x0, const float* __restrict__ t,
    const float* __restrict__ speed, const float* __restrict__ vola,
    const float* __restrict__ noise, const int* __restrict__ items,
    const u16* __restrict__ nbr8, const float* __restrict__ indeg,
    const int* __restrict__ pdeg, float* __restrict__ out)
{
    __shared__ float xb[2][NN + 8];   // double-buffered x; slot NN.. = 0 sentinel
    __shared__ float att[NN];         // feat[...,0] attempts
    __shared__ float suc[NN];         // feat[...,1] successes
    __shared__ float t_s[TT];
    __shared__ int   it_s[TT];

    const int s = blockIdx.x;
    const int n = threadIdx.x;

    if (n < TT) { t_s[n] = t[s * TT + n]; it_s[n] = items[s * TT + n]; }
    float x0n = x0[n];
    xb[0][n] = x0n;
    if (n < 8) { xb[0][NN + n] = 0.0f; xb[1][NN + n] = 0.0f; }
    int item0 = items[s * TT + 0];        // read directly so no barrier dependency
    att[n] = (n == item0) ? 1.0f : 0.0f;
    suc[n] = 0.0f;
    out[(size_t)(s * TT) * NN + n] = x0n; // x at t=0

    const float sp = speed[s];
    const float vo = vola[s];
    const float dg = indeg[n];
    const int ngrp = pdeg[n] >> 3;
    const float invdeg = 0.7f / (dg + 1e-7f);   // GAMMA / (in_deg + 1e-7)

    // this thread's neighbor groups: 16B apart per lane, 16KB stride per group
    const uint4* __restrict__ nb = (const uint4*)(nbr8 + (n << 3));

    __syncthreads();

    int cur = 0;
    for (int i = 0; i < TT - 1; ++i) {
        const float* __restrict__ xq = xb[cur];
        float dt = t_s[i + 1] - t_s[i];
        float e  = expf(-sp * dt);
        float sc = vo * sqrtf((1.0f - e * e) / (2.0f * sp + 1e-6f));
        float nz = noise[((size_t)s * (TT - 1) + i) * NN + n] * sc;

        float acc = 0.0f;
        for (int g = 0; g < ngrp; ++g) {
            uint4 w = nb[(size_t)g << 10];      // 8 ushort indices, one dwordx4
            acc += xq[w.x & 0xFFFF];
            acc += xq[w.x >> 16];
            acc += xq[w.y & 0xFFFF];
            acc += xq[w.y >> 16];
            acc += xq[w.z & 0xFFFF];
            acc += xq[w.z >> 16];
            acc += xq[w.w & 0xFFFF];
            acc += xq[w.w >> 16];
        }

        float a_f = att[n], s_f = suc[n];
        float r = s_f / (a_f + 1e-6f);                 // EPS
        float level = 0.5f * (acc * invdeg) + 0.5f * (r * r);  // OMEGA=0.5, RHO=2
        float xp = xq[n];
        float xn = fmaf(xp, e, fmaf(1.0f - e, level, nz));

        out[((size_t)s * TT + i + 1) * NN + n] = xn;
        xb[cur ^ 1][n] = xn;

        if (n == it_s[i + 1]) {                        // feat update (owner thread only)
            att[n] = a_f + 1.0f;
            suc[n] = s_f + (xn >= 0.0f ? 1.0f : 0.0f); // sigmoid(x)>=0.5 <=> x>=0
        }
        cur ^= 1;
        __syncthreads();
    }
}

extern "C" void kernel_launch(void* const* d_in, const int* in_sizes, int n_in,
                              void* d_out, int out_size, void* d_ws, size_t ws_size,
                              hipStream_t stream)
{
    const float* x0    = (const float*)d_in[0];
    const float* t     = (const float*)d_in[1];
    const float* speed = (const float*)d_in[2];
    const float* vola  = (const float*)d_in[3];
    const float* adj   = (const float*)d_in[4];
    const float* noise = (const float*)d_in[5];
    const int*   items = (const int*)d_in[6];
    float* out = (float*)d_out;

    char* ws = (char*)d_ws;
    float* indeg    = (float*)ws;            // 4 KB
    int*   pdeg     = (int*)(ws + 4096);     // 4 KB
    int*   cnt_part = (int*)(ws + 8192);     // 64 KB
    u16*   nbr8     = (u16*)(ws + 8192 + 65536); // 192 KB

    count_kernel<<<256, 64, 0, stream>>>(adj, cnt_part);
    fill_kernel<<<256, 64, 0, stream>>>(adj, cnt_part, nbr8, indeg, pdeg);
    sim_kernel<<<64, 1024, 0, stream>>>(x0, t, speed, vola, noise, items,
                                        nbr8, indeg, pdeg, out);
}